// Round 2
// baseline (861.766 us; speedup 1.0000x reference)
//
#include <hip/hip_runtime.h>
#include <stdint.h>

typedef __attribute__((ext_vector_type(8))) short bf16x8;   // 8 bf16 in 4 VGPRs
typedef __attribute__((ext_vector_type(4))) float f32x4;

__device__ __forceinline__ float b2f(uint32_t h) {
    union { uint32_t u; float f; } v; v.u = h << 16; return v.f;
}
__device__ __forceinline__ ushort f2b(float f) {
    union { float f; uint32_t u; } v; v.f = f;
    uint32_t u = v.u;
    return (ushort)((u + 0x7fffu + ((u >> 16) & 1u)) >> 16);
}
// read input float #i that is either fp32 or bf16 per flag
__device__ __forceinline__ float ldin(const void* p, int i, int fp32) {
    return fp32 ? ((const float*)p)[i] : b2f(((const ushort*)p)[i]);
}

// ---------------- dtype sniffer ----------------
// flags[0]=1 if float inputs are fp32 (else bf16); flags[1]=1 if indices are int64 (else int32)
__global__ void k_flags(const void* W1, const void* ei, int* flags) {
    if (threadIdx.x == 0 && blockIdx.x == 0) {
        int fp32 = 0;
        const ushort* w = (const ushort*)W1;   // W1 ~ U(-1/16,1/16): true bf16 values all tiny
        for (int i = 0; i < 128; ++i) {
            float a = fabsf(b2f(w[i]));
            if (!(a <= 0.25f)) fp32 = 1;       // random fp32 low-halves blow past this (or NaN)
        }
        int zeros = 0;
        const int* e = (const int*)ei;         // int64 little-endian: odd words are high=0
        for (int i = 0; i < 16; ++i) if (e[2 * i + 1] == 0) zeros++;
        flags[0] = fp32;
        flags[1] = (zeros >= 15) ? 1 : 0;
    }
}

// ---------------- canonicalize indices to clamped int32 ----------------
__global__ __launch_bounds__(256) void k_cvt_idx(const void* ei, const void* ep, const void* en,
                                                 int* cEi, int* cEp, int* cEn,
                                                 int twoE, int twoEp, int twoEn, int N,
                                                 const int* __restrict__ flags) {
    int i = blockIdx.x * 256 + threadIdx.x;
    int i64 = flags[1];
    const void* srcp; int* dstp; int j = i;
    if (i < twoE) { srcp = ei; dstp = cEi; }
    else if (i < twoE + twoEp) { srcp = ep; dstp = cEp; j = i - twoE; }
    else if (i < twoE + twoEp + twoEn) { srcp = en; dstp = cEn; j = i - twoE - twoEp; }
    else return;
    int v = i64 ? (int)((const long long*)srcp)[j] : ((const int*)srcp)[j];
    v = v < 0 ? 0 : (v >= N ? N - 1 : v);
    dstp[j] = v;
}

// ---------------- canonicalize weights (transpose) + biases to bf16 ----------------
// Wt1[c*256+k]=W1[k,c]; Wt2[c*128+k]=W2[k,c]; WtC[c*128+k]= c<10 ? Wcls[k,c] : 0 (c<16)
__global__ __launch_bounds__(256) void k_cvt_w(const void* W1, const void* W2, const void* Wc,
                                               const void* b1, const void* b2, const void* bc,
                                               const void* Wl, const void* bl,
                                               ushort* Wt1, ushort* Wt2, ushort* WtC,
                                               ushort* b1c, ushort* b2c, ushort* bcc,
                                               ushort* Wlc, ushort* blc,
                                               const int* __restrict__ flags) {
    int i = blockIdx.x * 256 + threadIdx.x;
    int f = flags[0];
    if (i < 32768) {
        int c = i >> 8, k = i & 255;
        Wt1[i] = f2b(ldin(W1, k * 128 + c, f));
    } else if (i < 49152) {
        int j = i - 32768, c = j >> 7, k = j & 127;
        Wt2[j] = f2b(ldin(W2, k * 128 + c, f));
    } else if (i < 51200) {
        int j = i - 49152, c = j >> 7, k = j & 127;
        ushort v = 0;
        if (c < 10) v = f2b(ldin(Wc, k * 10 + c, f));
        WtC[j] = v;
    } else if (i < 51328) {
        int j = i - 51200; b1c[j] = f2b(ldin(b1, j, f));
    } else if (i < 51456) {
        int j = i - 51328; b2c[j] = f2b(ldin(b2, j, f));
    } else if (i < 51472) {
        int j = i - 51456;
        ushort v = 0;
        if (j < 10) v = f2b(ldin(bc, j, f));
        bcc[j] = v;
    } else if (i < 51728) {
        int j = i - 51472; Wlc[j] = f2b(ldin(Wl, j, f));
    } else if (i < 51736) {
        int j = i - 51728;
        ushort v = 0;
        if (j < 1) v = f2b(ldin(bl, 0, f));
        blc[j] = v;
    }
}

// ---------------- canonicalize x to bf16 (only when fp32) ----------------
__global__ __launch_bounds__(256) void k_cvt_x(const void* x, ushort* xc, int total,
                                               const int* __restrict__ flags) {
    if (!flags[0]) return;
    int i = (blockIdx.x * 256 + threadIdx.x) * 4;
    if (i >= total) return;
    const float* xf = (const float*)x;
    float4 v = *(const float4*)(xf + i);
    xc[i + 0] = f2b(v.x); xc[i + 1] = f2b(v.y);
    xc[i + 2] = f2b(v.z); xc[i + 3] = f2b(v.w);
}

// ---------------- CSR build ----------------
__global__ __launch_bounds__(256) void k_count(const int* __restrict__ dst, int* __restrict__ deg, int E) {
    int i = blockIdx.x * 256 + threadIdx.x;
    if (i < E) atomicAdd(&deg[dst[i]], 1);
}

__global__ __launch_bounds__(1024) void k_scan_block(const int* __restrict__ deg, int* __restrict__ rowptr,
                                                     float* __restrict__ dinv, int* __restrict__ bsum, int n) {
    __shared__ int sh[1024];
    int t = threadIdx.x;
    int i = blockIdx.x * 1024 + t;
    int val = (i < n) ? deg[i] : 0;
    sh[t] = val; __syncthreads();
    for (int off = 1; off < 1024; off <<= 1) {
        int v = (t >= off) ? sh[t - off] : 0;
        __syncthreads();
        sh[t] += v;
        __syncthreads();
    }
    if (i < n) {
        rowptr[i] = sh[t] - val;
        dinv[i] = rsqrtf((float)(val + 1));
    }
    if (t == 1023) bsum[blockIdx.x] = sh[1023];
}

__global__ __launch_bounds__(128) void k_scan_top(const int* __restrict__ bsum, int* __restrict__ boff, int nb) {
    __shared__ int sh[128];
    int t = threadIdx.x;
    int val = (t < nb) ? bsum[t] : 0;
    sh[t] = val; __syncthreads();
    for (int off = 1; off < 128; off <<= 1) {
        int v = (t >= off) ? sh[t - off] : 0;
        __syncthreads();
        sh[t] += v;
        __syncthreads();
    }
    if (t < nb) boff[t] = sh[t] - val;
}

__global__ __launch_bounds__(1024) void k_scan_add(int* __restrict__ rowptr, const int* __restrict__ boff,
                                                   int n, int E) {
    int i = blockIdx.x * 1024 + threadIdx.x;
    if (i < n) rowptr[i] += boff[blockIdx.x];
    if (i == 0) rowptr[n] = E;
}

__global__ __launch_bounds__(256) void k_fill(const int* __restrict__ src, const int* __restrict__ dst,
                                              const int* __restrict__ rowptr, int* __restrict__ cursor,
                                              int* __restrict__ col, int E) {
    int i = blockIdx.x * 256 + threadIdx.x;
    if (i < E) {
        int d = dst[i];
        int p = rowptr[d] + atomicAdd(&cursor[d], 1);
        col[p] = src[i];
    }
}

// ---------------- MFMA GEMM: Out[N,128] = X[N,K] @ W[K,128] (Wt = W^T) ----------------
template <int K, bool SEL>
__global__ __launch_bounds__(256) void k_gemm(const void* Xraw, const ushort* __restrict__ Xc,
                                              const int* __restrict__ flags,
                                              const ushort* __restrict__ Wt,
                                              ushort* __restrict__ Out, int nrows) {
    const ushort* Xp = SEL ? (flags[0] ? Xc : (const ushort*)Xraw) : (const ushort*)Xraw;
    int wave = threadIdx.x >> 6;
    int gw = blockIdx.x * 4 + wave;
    if (gw * 16 >= nrows) return;
    int l = threadIdx.x & 63;
    int q = l >> 4, mr = l & 15;
    int m0 = gw * 16;

    f32x4 acc[8];
#pragma unroll
    for (int n = 0; n < 8; ++n) acc[n] = (f32x4){0.f, 0.f, 0.f, 0.f};

    const ushort* xrow = Xp + (size_t)(m0 + mr) * K + q * 8;
#pragma unroll
    for (int s = 0; s < K / 32; ++s) {
        bf16x8 a = *(const bf16x8*)(xrow + s * 32);
#pragma unroll
        for (int n = 0; n < 8; ++n) {
            bf16x8 b = *(const bf16x8*)(Wt + (size_t)(n * 16 + mr) * K + s * 32 + q * 8);
            acc[n] = __builtin_amdgcn_mfma_f32_16x16x32_bf16(a, b, acc[n], 0, 0, 0);
        }
    }
#pragma unroll
    for (int n = 0; n < 8; ++n) {
#pragma unroll
        for (int r = 0; r < 4; ++r) {
            int row = m0 + q * 4 + r;
            Out[(size_t)row * 128 + n * 16 + mr] = f2b(acc[n][r]);
        }
    }
}

// ---------------- GCN aggregate: one wave per dst node ----------------
__global__ __launch_bounds__(256) void k_conv(const ushort* __restrict__ XW, const int* __restrict__ rowptr,
                                              const int* __restrict__ col, const float* __restrict__ dinv,
                                              const ushort* __restrict__ bias, ushort* __restrict__ Hout,
                                              int n, int relu) {
    int wave = threadIdx.x >> 6;
    int v = blockIdx.x * 4 + wave;
    if (v >= n) return;
    int l = threadIdx.x & 63;

    float dv = dinv[v];
    int s0 = rowptr[v], s1 = rowptr[v + 1];

    uint32_t pv = *(const uint32_t*)(XW + (size_t)v * 128 + 2 * l);
    float wself = dv * dv;
    float acc0 = b2f(pv & 0xffffu) * wself;
    float acc1 = b2f(pv >> 16) * wself;

    for (int i = s0; i < s1; ++i) {
        int s = col[i];
        float wn = dinv[s] * dv;
        uint32_t p = *(const uint32_t*)(XW + (size_t)s * 128 + 2 * l);
        acc0 += b2f(p & 0xffffu) * wn;
        acc1 += b2f(p >> 16) * wn;
    }

    uint32_t bb = *(const uint32_t*)(bias + 2 * l);
    acc0 += b2f(bb & 0xffffu);
    acc1 += b2f(bb >> 16);
    if (relu) { acc0 = fmaxf(acc0, 0.f); acc1 = fmaxf(acc1, 0.f); }

    uint32_t o = (uint32_t)f2b(acc0) | ((uint32_t)f2b(acc1) << 16);
    *(uint32_t*)(Hout + (size_t)v * 128 + 2 * l) = o;
}

// ---------------- node head: logits = relu(h)@Wcls + bcls ; log_softmax over 10 ----------------
__global__ __launch_bounds__(256) void k_nodehead(const ushort* __restrict__ H, const ushort* __restrict__ WtC,
                                                  const ushort* __restrict__ bcc, void* __restrict__ out,
                                                  int n, const int* __restrict__ flags) {
    int wave = threadIdx.x >> 6;
    int gw = blockIdx.x * 4 + wave;
    if (gw * 16 >= n) return;
    int fp32o = flags[0];
    int l = threadIdx.x & 63;
    int q = l >> 4, mr = l & 15;
    int m0 = gw * 16;

    f32x4 acc = (f32x4){0.f, 0.f, 0.f, 0.f};
    const ushort* hrow = H + (size_t)(m0 + mr) * 128 + q * 8;
#pragma unroll
    for (int s = 0; s < 4; ++s) {
        bf16x8 a = *(const bf16x8*)(hrow + s * 32);
#pragma unroll
        for (int j = 0; j < 8; ++j) {
            ushort t = (ushort)a[j];
            if (t & 0x8000u) a[j] = 0;   // relu on bf16
        }
        bf16x8 b = *(const bf16x8*)(WtC + (size_t)mr * 128 + s * 32 + q * 8);
        acc = __builtin_amdgcn_mfma_f32_16x16x32_bf16(a, b, acc, 0, 0, 0);
    }

    float bc = b2f(bcc[mr]);  // padded to 16, zeros beyond 10
#pragma unroll
    for (int r = 0; r < 4; ++r) {
        float logit = acc[r] + bc;
        float m = (mr < 10) ? logit : -1e30f;
#pragma unroll
        for (int off = 1; off < 16; off <<= 1) m = fmaxf(m, __shfl_xor(m, off, 16));
        float ex = (mr < 10) ? expf(logit - m) : 0.f;
        float ssum = ex;
#pragma unroll
        for (int off = 1; off < 16; off <<= 1) ssum += __shfl_xor(ssum, off, 16);
        if (mr < 10) {
            float lsm = logit - m - logf(ssum);
            size_t idx = (size_t)(m0 + q * 4 + r) * 10 + mr;
            if (fp32o) ((float*)out)[idx] = lsm;
            else ((ushort*)out)[idx] = f2b(lsm);
        }
    }
}

// ---------------- link head: one wave per (pos|neg) edge ----------------
__global__ __launch_bounds__(256) void k_link(const ushort* __restrict__ H, const int* __restrict__ pos,
                                              const int* __restrict__ neg, const ushort* __restrict__ Wlc,
                                              const ushort* __restrict__ blc, void* __restrict__ out,
                                              size_t obase, int Ep, int En, const int* __restrict__ flags) {
    int wave = threadIdx.x >> 6;
    int e = blockIdx.x * 4 + wave;
    if (e >= Ep + En) return;
    int fp32o = flags[0];
    int l = threadIdx.x & 63;

    int sI, dI; size_t slot;
    if (e < Ep) { sI = pos[e]; dI = pos[Ep + e]; slot = (size_t)e; }
    else { int e2 = e - Ep; sI = neg[e2]; dI = neg[En + e2]; slot = (size_t)Ep + e2; }

    uint32_t ps = *(const uint32_t*)(H + (size_t)sI * 128 + 2 * l);
    uint32_t pd = *(const uint32_t*)(H + (size_t)dI * 128 + 2 * l);
    uint32_t w0 = *(const uint32_t*)(Wlc + 2 * l);
    uint32_t w1 = *(const uint32_t*)(Wlc + 128 + 2 * l);

    float acc = b2f(ps & 0xffffu) * b2f(w0 & 0xffffu) + b2f(ps >> 16) * b2f(w0 >> 16)
              + b2f(pd & 0xffffu) * b2f(w1 & 0xffffu) + b2f(pd >> 16) * b2f(w1 >> 16);
#pragma unroll
    for (int off = 32; off > 0; off >>= 1) acc += __shfl_xor(acc, off, 64);
    if (l == 0) {
        float v = acc + b2f(blc[0]);
        size_t idx = obase + slot;
        if (fp32o) ((float*)out)[idx] = v;
        else ((ushort*)out)[idx] = f2b(v);
    }
}

extern "C" void kernel_launch(void* const* d_in, const int* in_sizes, int n_in,
                              void* d_out, int out_size, void* d_ws, size_t ws_size,
                              hipStream_t stream) {
    const void* x    = d_in[0];
    const void* ei   = d_in[1];
    const void* eip  = d_in[2];
    const void* ein  = d_in[3];
    const void* W1   = d_in[4];
    const void* b1   = d_in[5];
    const void* W2   = d_in[6];
    const void* b2   = d_in[7];
    const void* Wcls = d_in[8];
    const void* bcls = d_in[9];
    const void* Wl   = d_in[10];
    const void* bl   = d_in[11];

    const int N  = in_sizes[0] / 256;
    const int E  = in_sizes[1] / 2;
    const int Ep = in_sizes[2] / 2;
    const int En = in_sizes[3] / 2;

    char* ws = (char*)d_ws;
    size_t off = 0;
    auto alloc = [&](size_t bytes) -> void* {
        void* p = ws + off;
        off = (off + bytes + 255) & ~(size_t)255;
        return p;
    };
    int*    flags = (int*)alloc(256);
    ushort* xc    = (ushort*)alloc((size_t)N * 256 * 2);
    ushort* bufXW = (ushort*)alloc((size_t)N * 128 * 2);
    ushort* bufH  = (ushort*)alloc((size_t)N * 128 * 2);
    int*    cEi   = (int*)alloc((size_t)2 * E * 4);
    int*    cEp   = (int*)alloc((size_t)2 * Ep * 4);
    int*    cEn   = (int*)alloc((size_t)2 * En * 4);
    float*  dinv  = (float*)alloc((size_t)N * 4);
    int*    deg   = (int*)alloc((size_t)N * 4);
    int*    cur   = (int*)alloc((size_t)N * 4);
    int*    rowp  = (int*)alloc((size_t)(N + 1) * 4);
    int*    col   = (int*)alloc((size_t)E * 4);
    int*    bsum  = (int*)alloc(1024);
    int*    boff  = (int*)alloc(1024);
    ushort* Wt1   = (ushort*)alloc(65536);
    ushort* Wt2   = (ushort*)alloc(32768);
    ushort* WtC   = (ushort*)alloc(4096);
    ushort* b1c   = (ushort*)alloc(256);
    ushort* b2c   = (ushort*)alloc(256);
    ushort* bcc   = (ushort*)alloc(64);
    ushort* Wlc   = (ushort*)alloc(512);
    ushort* blc   = (ushort*)alloc(64);

    hipMemsetAsync(deg, 0, (size_t)N * 4, stream);
    hipMemsetAsync(cur, 0, (size_t)N * 4, stream);

    k_flags<<<1, 64, 0, stream>>>(W1, ei, flags);

    int twoE = 2 * E, twoEp = 2 * Ep, twoEn = 2 * En;
    int idx_total = twoE + twoEp + twoEn;
    k_cvt_idx<<<(idx_total + 255) / 256, 256, 0, stream>>>(ei, eip, ein, cEi, cEp, cEn,
                                                           twoE, twoEp, twoEn, N, flags);
    k_cvt_w<<<203, 256, 0, stream>>>(W1, W2, Wcls, b1, b2, bcls, Wl, bl,
                                     Wt1, Wt2, WtC, b1c, b2c, bcc, Wlc, blc, flags);
    k_cvt_x<<<((N * 256 / 4) + 255) / 256, 256, 0, stream>>>(x, xc, N * 256, flags);

    const int* srcp = cEi;
    const int* dstp = cEi + E;
    k_count<<<(E + 255) / 256, 256, 0, stream>>>(dstp, deg, E);
    int nb = (N + 1023) / 1024;
    k_scan_block<<<nb, 1024, 0, stream>>>(deg, rowp, dinv, bsum, N);
    k_scan_top<<<1, 128, 0, stream>>>(bsum, boff, nb);
    k_scan_add<<<nb, 1024, 0, stream>>>(rowp, boff, N, E);
    k_fill<<<(E + 255) / 256, 256, 0, stream>>>(srcp, dstp, rowp, cur, col, E);

    int gemm_blocks = ((N + 15) / 16 + 3) / 4;
    k_gemm<256, true><<<gemm_blocks, 256, 0, stream>>>(x, xc, flags, Wt1, bufXW, N);
    k_conv<<<(N + 3) / 4, 256, 0, stream>>>(bufXW, rowp, col, dinv, b1c, bufH, N, 1);
    k_gemm<128, false><<<gemm_blocks, 256, 0, stream>>>(bufH, bufH, flags, Wt2, bufXW, N);
    k_conv<<<(N + 3) / 4, 256, 0, stream>>>(bufXW, rowp, col, dinv, b2c, bufH, N, 0);

    k_nodehead<<<gemm_blocks, 256, 0, stream>>>(bufH, WtC, bcc, d_out, N, flags);
    k_link<<<(Ep + En + 3) / 4, 256, 0, stream>>>(bufH, cEp, cEn, Wlc, blc, d_out,
                                                  (size_t)N * 10, Ep, En, flags);
}

// Round 3
// 601.025 us; speedup vs baseline: 1.4338x; 1.4338x over previous
//
#include <hip/hip_runtime.h>
#include <stdint.h>

typedef __attribute__((ext_vector_type(8))) short bf16x8;   // 8 bf16 in 4 VGPRs
typedef __attribute__((ext_vector_type(4))) float f32x4;

__device__ __forceinline__ float b2f(uint32_t h) {
    union { uint32_t u; float f; } v; v.u = h << 16; return v.f;
}
__device__ __forceinline__ ushort f2b(float f) {
    union { float f; uint32_t u; } v; v.f = f;
    uint32_t u = v.u;
    return (ushort)((u + 0x7fffu + ((u >> 16) & 1u)) >> 16);
}
__device__ __forceinline__ float ldin(const void* p, int i, int fp32) {
    return fp32 ? ((const float*)p)[i] : b2f(((const ushort*)p)[i]);
}

// ---------------- dtype sniffer (64 lanes) ----------------
__global__ void k_flags(const void* W1, const void* ei, int* flags) {
    int l = threadIdx.x;
    const ushort* w = (const ushort*)W1;   // W1 ~ U(-1/16,1/16) if true bf16
    float a0 = fabsf(b2f(w[l]));
    float a1 = fabsf(b2f(w[64 + l]));
    bool bad = !(a0 <= 0.25f) || !(a1 <= 0.25f);
    unsigned long long mb = __ballot(bad);
    const int* e = (const int*)ei;         // int64: odd (high) words are 0
    bool z = (l < 16) ? (e[2 * l + 1] == 0) : false;
    unsigned long long mz = __ballot(z);
    if (l == 0) {
        flags[0] = mb ? 1 : 0;                                // fp32 floats?
        flags[1] = (__popcll(mz & 0xffffull) >= 15) ? 1 : 0;  // int64 indices?
    }
}

// ---------------- indices -> clamped int32 (+ fused degree count on dst half) ----------------
__global__ __launch_bounds__(256) void k_cvt_idx(const void* ei, const void* ep, const void* en,
                                                 int* cEi, int* cEp, int* cEn, int* __restrict__ deg,
                                                 int twoE, int twoEp, int twoEn, int N,
                                                 const int* __restrict__ flags) {
    int i = blockIdx.x * 256 + threadIdx.x;
    int i64 = flags[1];
    const void* srcp; int* dstp; int j = i; bool isdst = false;
    if (i < twoE) { srcp = ei; dstp = cEi; isdst = (i >= (twoE >> 1)); }
    else if (i < twoE + twoEp) { srcp = ep; dstp = cEp; j = i - twoE; }
    else if (i < twoE + twoEp + twoEn) { srcp = en; dstp = cEn; j = i - twoE - twoEp; }
    else return;
    int v = i64 ? (int)((const long long*)srcp)[j] : ((const int*)srcp)[j];
    v = v < 0 ? 0 : (v >= N ? N - 1 : v);
    dstp[j] = v;
    if (isdst) atomicAdd(&deg[v], 1);
}

// ---------------- weights (transpose) + biases -> bf16 ----------------
__global__ __launch_bounds__(256) void k_cvt_w(const void* W1, const void* W2, const void* Wc,
                                               const void* b1, const void* b2, const void* bc,
                                               const void* Wl, const void* bl,
                                               ushort* Wt1, ushort* Wt2, ushort* WtC,
                                               ushort* b1c, ushort* b2c, ushort* bcc,
                                               ushort* Wlc, ushort* blc,
                                               const int* __restrict__ flags) {
    int i = blockIdx.x * 256 + threadIdx.x;
    int f = flags[0];
    if (i < 32768) {
        int c = i >> 8, k = i & 255;
        Wt1[i] = f2b(ldin(W1, k * 128 + c, f));
    } else if (i < 49152) {
        int j = i - 32768, c = j >> 7, k = j & 127;
        Wt2[j] = f2b(ldin(W2, k * 128 + c, f));
    } else if (i < 51200) {
        int j = i - 49152, c = j >> 7, k = j & 127;
        ushort v = 0;
        if (c < 10) v = f2b(ldin(Wc, k * 10 + c, f));
        WtC[j] = v;
    } else if (i < 51328) {
        int j = i - 51200; b1c[j] = f2b(ldin(b1, j, f));
    } else if (i < 51456) {
        int j = i - 51328; b2c[j] = f2b(ldin(b2, j, f));
    } else if (i < 51472) {
        int j = i - 51456;
        ushort v = 0;
        if (j < 10) v = f2b(ldin(bc, j, f));
        bcc[j] = v;
    } else if (i < 51728) {
        int j = i - 51472; Wlc[j] = f2b(ldin(Wl, j, f));
    } else if (i < 51736) {
        int j = i - 51728;
        ushort v = 0;
        if (j < 1) v = f2b(ldin(bl, 0, f));
        blc[j] = v;
    }
}

// ---------------- CSR scan ----------------
__global__ __launch_bounds__(1024) void k_scan_block(const int* __restrict__ deg, int* __restrict__ rowptr,
                                                     float* __restrict__ dinv, int* __restrict__ bsum, int n) {
    __shared__ int sh[1024];
    int t = threadIdx.x;
    int i = blockIdx.x * 1024 + t;
    int val = (i < n) ? deg[i] : 0;
    sh[t] = val; __syncthreads();
    for (int off = 1; off < 1024; off <<= 1) {
        int v = (t >= off) ? sh[t - off] : 0;
        __syncthreads();
        sh[t] += v;
        __syncthreads();
    }
    if (i < n) {
        rowptr[i] = sh[t] - val;
        dinv[i] = rsqrtf((float)(val + 1));
    }
    if (t == 1023) bsum[blockIdx.x] = sh[1023];
}

__global__ __launch_bounds__(128) void k_scan_top(const int* __restrict__ bsum, int* __restrict__ boff, int nb) {
    __shared__ int sh[128];
    int t = threadIdx.x;
    int val = (t < nb) ? bsum[t] : 0;
    sh[t] = val; __syncthreads();
    for (int off = 1; off < 128; off <<= 1) {
        int v = (t >= off) ? sh[t - off] : 0;
        __syncthreads();
        sh[t] += v;
        __syncthreads();
    }
    if (t < nb) boff[t] = sh[t] - val;
}

__global__ __launch_bounds__(1024) void k_scan_add(int* __restrict__ rowptr, const int* __restrict__ boff,
                                                   int n, int E) {
    int i = blockIdx.x * 1024 + threadIdx.x;
    if (i < n) rowptr[i] += boff[blockIdx.x];
    if (i == 0) rowptr[n] = E;
}

// ---------------- CSR fill: edge = {src, dinv[src]*dinv[dst]} ----------------
__global__ __launch_bounds__(256) void k_fill(const int* __restrict__ src, const int* __restrict__ dst,
                                              const int* __restrict__ rowptr, int* __restrict__ cursor,
                                              int2* __restrict__ edge, const float* __restrict__ dinv, int E) {
    int i = blockIdx.x * 256 + threadIdx.x;
    if (i < E) {
        int d = dst[i];
        int s = src[i];
        int p = rowptr[d] + atomicAdd(&cursor[d], 1);
        float w = dinv[s] * dinv[d];
        edge[p] = make_int2(s, __float_as_int(w));
    }
}

// ---------------- MFMA GEMM: Out[N,128] = X[N,K] @ W[K,128] (Wt = W^T); A may be fp32 ----------------
template <int K, bool MAYBE_F32>
__global__ __launch_bounds__(256) void k_gemm(const void* __restrict__ X,
                                              const int* __restrict__ flags,
                                              const ushort* __restrict__ Wt,
                                              ushort* __restrict__ Out, int nrows) {
    int wave = threadIdx.x >> 6;
    int gw = blockIdx.x * 4 + wave;
    if (gw * 16 >= nrows) return;
    int l = threadIdx.x & 63;
    int q = l >> 4, mr = l & 15;
    int m0 = gw * 16;

    f32x4 acc[8];
#pragma unroll
    for (int n = 0; n < 8; ++n) acc[n] = (f32x4){0.f, 0.f, 0.f, 0.f};

    bool f32in = MAYBE_F32 && flags[0];
    if (f32in) {
        const float* xrow = (const float*)X + (size_t)(m0 + mr) * K + q * 8;
#pragma unroll
        for (int s = 0; s < K / 32; ++s) {
            float4 lo = *(const float4*)(xrow + s * 32);
            float4 hi = *(const float4*)(xrow + s * 32 + 4);
            bf16x8 a;
            a[0] = (short)f2b(lo.x); a[1] = (short)f2b(lo.y);
            a[2] = (short)f2b(lo.z); a[3] = (short)f2b(lo.w);
            a[4] = (short)f2b(hi.x); a[5] = (short)f2b(hi.y);
            a[6] = (short)f2b(hi.z); a[7] = (short)f2b(hi.w);
#pragma unroll
            for (int n = 0; n < 8; ++n) {
                bf16x8 b = *(const bf16x8*)(Wt + (size_t)(n * 16 + mr) * K + s * 32 + q * 8);
                acc[n] = __builtin_amdgcn_mfma_f32_16x16x32_bf16(a, b, acc[n], 0, 0, 0);
            }
        }
    } else {
        const ushort* xrow = (const ushort*)X + (size_t)(m0 + mr) * K + q * 8;
#pragma unroll
        for (int s = 0; s < K / 32; ++s) {
            bf16x8 a = *(const bf16x8*)(xrow + s * 32);
#pragma unroll
            for (int n = 0; n < 8; ++n) {
                bf16x8 b = *(const bf16x8*)(Wt + (size_t)(n * 16 + mr) * K + s * 32 + q * 8);
                acc[n] = __builtin_amdgcn_mfma_f32_16x16x32_bf16(a, b, acc[n], 0, 0, 0);
            }
        }
    }
#pragma unroll
    for (int n = 0; n < 8; ++n) {
#pragma unroll
        for (int r = 0; r < 4; ++r) {
            int row = m0 + q * 4 + r;
            Out[(size_t)row * 128 + n * 16 + mr] = f2b(acc[n][r]);
        }
    }
}

// ---------------- GCN aggregate: one wave per dst node, 8 edges in flight ----------------
__global__ __launch_bounds__(256) void k_conv(const ushort* __restrict__ XW, const int* __restrict__ rowptr,
                                              const int2* __restrict__ edge, const float* __restrict__ dinv,
                                              const ushort* __restrict__ bias, ushort* __restrict__ Hout,
                                              int n, int relu) {
    int wave = threadIdx.x >> 6;
    int v = blockIdx.x * 4 + wave;
    if (v >= n) return;
    int l = threadIdx.x & 63;

    int s0 = rowptr[v], s1 = rowptr[v + 1];
    float dv = dinv[v];
    uint32_t pv = *(const uint32_t*)(XW + (size_t)v * 128 + 2 * l);
    float wself = dv * dv;
    float acc0 = b2f(pv & 0xffffu) * wself;
    float acc1 = b2f(pv >> 16) * wself;

    int i = s0;
    while (i + 8 <= s1) {
        int2 e0[8];
#pragma unroll
        for (int j = 0; j < 8; ++j) e0[j] = edge[i + j];
        uint32_t p[8];
#pragma unroll
        for (int j = 0; j < 8; ++j)
            p[j] = *(const uint32_t*)(XW + (size_t)e0[j].x * 128 + 2 * l);
#pragma unroll
        for (int j = 0; j < 8; ++j) {
            float w = __int_as_float(e0[j].y);
            acc0 += b2f(p[j] & 0xffffu) * w;
            acc1 += b2f(p[j] >> 16) * w;
        }
        i += 8;
    }
    if (i < s1) {   // single predicated batch for the tail (<8)
        int2 e0[8];
#pragma unroll
        for (int j = 0; j < 8; ++j) e0[j] = edge[(i + j < s1) ? (i + j) : s0];
        uint32_t p[8];
#pragma unroll
        for (int j = 0; j < 8; ++j)
            p[j] = *(const uint32_t*)(XW + (size_t)e0[j].x * 128 + 2 * l);
#pragma unroll
        for (int j = 0; j < 8; ++j) {
            float w = (i + j < s1) ? __int_as_float(e0[j].y) : 0.f;
            acc0 += b2f(p[j] & 0xffffu) * w;
            acc1 += b2f(p[j] >> 16) * w;
        }
    }

    uint32_t bb = *(const uint32_t*)(bias + 2 * l);
    acc0 += b2f(bb & 0xffffu);
    acc1 += b2f(bb >> 16);
    if (relu) { acc0 = fmaxf(acc0, 0.f); acc1 = fmaxf(acc1, 0.f); }

    uint32_t o = (uint32_t)f2b(acc0) | ((uint32_t)f2b(acc1) << 16);
    *(uint32_t*)(Hout + (size_t)v * 128 + 2 * l) = o;
}

// ---------------- node head ----------------
__global__ __launch_bounds__(256) void k_nodehead(const ushort* __restrict__ H, const ushort* __restrict__ WtC,
                                                  const ushort* __restrict__ bcc, void* __restrict__ out,
                                                  int n, const int* __restrict__ flags) {
    int wave = threadIdx.x >> 6;
    int gw = blockIdx.x * 4 + wave;
    if (gw * 16 >= n) return;
    int fp32o = flags[0];
    int l = threadIdx.x & 63;
    int q = l >> 4, mr = l & 15;
    int m0 = gw * 16;

    f32x4 acc = (f32x4){0.f, 0.f, 0.f, 0.f};
    const ushort* hrow = H + (size_t)(m0 + mr) * 128 + q * 8;
#pragma unroll
    for (int s = 0; s < 4; ++s) {
        bf16x8 a = *(const bf16x8*)(hrow + s * 32);
#pragma unroll
        for (int j = 0; j < 8; ++j) {
            ushort t = (ushort)a[j];
            if (t & 0x8000u) a[j] = 0;   // relu on bf16
        }
        bf16x8 b = *(const bf16x8*)(WtC + (size_t)mr * 128 + s * 32 + q * 8);
        acc = __builtin_amdgcn_mfma_f32_16x16x32_bf16(a, b, acc, 0, 0, 0);
    }

    float bc = b2f(bcc[mr]);
#pragma unroll
    for (int r = 0; r < 4; ++r) {
        float logit = acc[r] + bc;
        float m = (mr < 10) ? logit : -1e30f;
#pragma unroll
        for (int off = 1; off < 16; off <<= 1) m = fmaxf(m, __shfl_xor(m, off, 16));
        float ex = (mr < 10) ? expf(logit - m) : 0.f;
        float ssum = ex;
#pragma unroll
        for (int off = 1; off < 16; off <<= 1) ssum += __shfl_xor(ssum, off, 16);
        if (mr < 10) {
            float lsm = logit - m - logf(ssum);
            size_t idx = (size_t)(m0 + q * 4 + r) * 10 + mr;
            if (fp32o) ((float*)out)[idx] = lsm;
            else ((ushort*)out)[idx] = f2b(lsm);
        }
    }
}

// ---------------- link head: 4 edges per wave, 16 lanes x dwordx4 per row ----------------
__global__ __launch_bounds__(256) void k_link(const ushort* __restrict__ H, const int* __restrict__ pos,
                                              const int* __restrict__ neg, const ushort* __restrict__ Wlc,
                                              const ushort* __restrict__ blc, void* __restrict__ out,
                                              size_t obase, int Ep, int En, const int* __restrict__ flags) {
    int wave = threadIdx.x >> 6;
    int l = threadIdx.x & 63;
    int g = l >> 4, t = l & 15;
    int e = (blockIdx.x * 4 + wave) * 4 + g;
    if (e >= Ep + En) return;
    int fp32o = flags[0];

    const int* P; int eb, off2;
    if (e < Ep) { P = pos; eb = e; off2 = Ep; }
    else { P = neg; eb = e - Ep; off2 = En; }
    int sI = P[eb], dI = P[off2 + eb];

    bf16x8 hs = *(const bf16x8*)(H + (size_t)sI * 128 + t * 8);
    bf16x8 hd = *(const bf16x8*)(H + (size_t)dI * 128 + t * 8);
    bf16x8 w0 = *(const bf16x8*)(Wlc + t * 8);
    bf16x8 w1 = *(const bf16x8*)(Wlc + 128 + t * 8);

    float acc = 0.f;
#pragma unroll
    for (int j = 0; j < 8; ++j) {
        acc += b2f((ushort)hs[j]) * b2f((ushort)w0[j]);
        acc += b2f((ushort)hd[j]) * b2f((ushort)w1[j]);
    }
#pragma unroll
    for (int off = 1; off < 16; off <<= 1) acc += __shfl_xor(acc, off, 16);
    if (t == 0) {
        float vf = acc + b2f(blc[0]);
        size_t idx = obase + (size_t)e;
        if (fp32o) ((float*)out)[idx] = vf;
        else ((ushort*)out)[idx] = f2b(vf);
    }
}

extern "C" void kernel_launch(void* const* d_in, const int* in_sizes, int n_in,
                              void* d_out, int out_size, void* d_ws, size_t ws_size,
                              hipStream_t stream) {
    const void* x    = d_in[0];
    const void* ei   = d_in[1];
    const void* eip  = d_in[2];
    const void* ein  = d_in[3];
    const void* W1   = d_in[4];
    const void* b1   = d_in[5];
    const void* W2   = d_in[6];
    const void* b2   = d_in[7];
    const void* Wcls = d_in[8];
    const void* bcls = d_in[9];
    const void* Wl   = d_in[10];
    const void* bl   = d_in[11];

    const int N  = in_sizes[0] / 256;
    const int E  = in_sizes[1] / 2;
    const int Ep = in_sizes[2] / 2;
    const int En = in_sizes[3] / 2;

    char* ws = (char*)d_ws;
    size_t off = 0;
    auto alloc = [&](size_t bytes) -> void* {
        void* p = ws + off;
        off = (off + bytes + 255) & ~(size_t)255;
        return p;
    };
    int*    flags = (int*)alloc(256);
    ushort* bufXW = (ushort*)alloc((size_t)N * 128 * 2);
    ushort* bufH  = (ushort*)alloc((size_t)N * 128 * 2);
    int*    cEi   = (int*)alloc((size_t)2 * E * 4);
    int*    cEp   = (int*)alloc((size_t)2 * Ep * 4);
    int*    cEn   = (int*)alloc((size_t)2 * En * 4);
    float*  dinv  = (float*)alloc((size_t)N * 4);
    int*    deg   = (int*)alloc((size_t)N * 4);
    int*    cur   = (int*)alloc((size_t)N * 4);
    int*    rowp  = (int*)alloc((size_t)(N + 1) * 4);
    int2*   edge  = (int2*)alloc((size_t)E * 8);
    int*    bsum  = (int*)alloc(1024);
    int*    boff  = (int*)alloc(1024);
    ushort* Wt1   = (ushort*)alloc(65536);
    ushort* Wt2   = (ushort*)alloc(32768);
    ushort* WtC   = (ushort*)alloc(4096);
    ushort* b1c   = (ushort*)alloc(256);
    ushort* b2c   = (ushort*)alloc(256);
    ushort* bcc   = (ushort*)alloc(64);
    ushort* Wlc   = (ushort*)alloc(512);
    ushort* blc   = (ushort*)alloc(64);

    hipMemsetAsync(deg, 0, (size_t)N * 4, stream);
    hipMemsetAsync(cur, 0, (size_t)N * 4, stream);

    k_flags<<<1, 64, 0, stream>>>(W1, ei, flags);

    int twoE = 2 * E, twoEp = 2 * Ep, twoEn = 2 * En;
    int idx_total = twoE + twoEp + twoEn;
    k_cvt_idx<<<(idx_total + 255) / 256, 256, 0, stream>>>(ei, eip, ein, cEi, cEp, cEn, deg,
                                                           twoE, twoEp, twoEn, N, flags);
    k_cvt_w<<<203, 256, 0, stream>>>(W1, W2, Wcls, b1, b2, bcls, Wl, bl,
                                     Wt1, Wt2, WtC, b1c, b2c, bcc, Wlc, blc, flags);

    const int* srcp = cEi;
    const int* dstp = cEi + E;
    int nb = (N + 1023) / 1024;
    k_scan_block<<<nb, 1024, 0, stream>>>(deg, rowp, dinv, bsum, N);
    k_scan_top<<<1, 128, 0, stream>>>(bsum, boff, nb);
    k_scan_add<<<nb, 1024, 0, stream>>>(rowp, boff, N, E);
    k_fill<<<(E + 255) / 256, 256, 0, stream>>>(srcp, dstp, rowp, cur, edge, dinv, E);

    int gemm_blocks = ((N + 15) / 16 + 3) / 4;
    k_gemm<256, true><<<gemm_blocks, 256, 0, stream>>>(x, flags, Wt1, bufXW, N);
    k_conv<<<(N + 3) / 4, 256, 0, stream>>>(bufXW, rowp, edge, dinv, b1c, bufH, N, 1);
    k_gemm<128, false><<<gemm_blocks, 256, 0, stream>>>(bufH, flags, Wt2, bufXW, N);
    k_conv<<<(N + 3) / 4, 256, 0, stream>>>(bufXW, rowp, edge, dinv, b2c, bufH, N, 0);

    k_nodehead<<<gemm_blocks, 256, 0, stream>>>(bufH, WtC, bcc, d_out, N, flags);
    k_link<<<(Ep + En + 3) / 4, 256, 0, stream>>>(bufH, cEp, cEn, Wlc, blc, d_out,
                                                  (size_t)N * 10, Ep, En, flags);
}